// Round 1
// baseline (477.596 us; speedup 1.0000x reference)
//
#include <hip/hip_runtime.h>
#include <math.h>

#define NN 131072
#define BBG 1024
#define MMN 128
#define DDF 256
#define KKC 32

// ---- d_out offsets (floats), concatenated in reference return order ----
#define OFF_S      0
#define OFF_HFLAT  4194304
#define OFF_HDENSE 12582912
#define OFF_P      20971520
#define OFF_PHAT   22020096
#define OFF_ZD     23068672
#define OFF_G      56623104
#define OFF_MASK   56885248
#define OFF_UNEW   56918016

// ---- ws offsets (floats) ----
#define WS_PSUM  0          // [2048][256]
#define WS_PSQ   524288     // [2048][256]
#define WS_TMP   1048576    // [16][256]
#define WS_SCALE 1052672    // [256]
#define WS_SHIFT 1052928    // [256]
#define WS_UN    1053184    // [32][256]
#define WS_SF    1061376    // [N][32]
#define WS_C     5255680    // [B][32]
#define WS_PART  5288448    // [8*32][256]

// ============ K1: h1 = z@W1 + b1 (f32), + per-block column stats ============
// 64 rows x 256 cols per block, 256 threads, 8x8 acc/thread.
// Thread owns cols c0..c0+3 and c0+128..c0+131 (split halves -> conflict-free b128 W reads).
__global__ __launch_bounds__(256) void k1_gemm1(
    const float* __restrict__ z, const float* __restrict__ W1,
    const float* __restrict__ b1, float* __restrict__ h1,
    float* __restrict__ psum, float* __restrict__ psq)
{
  __shared__ float As[64*32];
  __shared__ float Ws[32*256];
  __shared__ float red[8*256];
  const int t = threadIdx.x;
  const int n0 = blockIdx.x * 64;
  const int c0 = (t & 31) * 4;
  const int r0 = (t >> 5) * 8;

  float acc[8][8];
  #pragma unroll
  for (int i = 0; i < 8; ++i)
    #pragma unroll
    for (int j = 0; j < 8; ++j) acc[i][j] = 0.0f;

  for (int kk = 0; kk < 8; ++kk) {
    #pragma unroll
    for (int i = 0; i < 2; ++i) {
      int id = t + i*256;
      int row = id >> 3, seg = id & 7;
      *(float4*)(&As[row*32 + seg*4]) =
          *(const float4*)(z + (n0+row)*DDF + kk*32 + seg*4);
    }
    #pragma unroll
    for (int i = 0; i < 8; ++i) {
      int id = t + i*256;
      int row = id >> 6, seg = id & 63;
      *(float4*)(&Ws[row*256 + seg*4]) =
          *(const float4*)(W1 + (kk*32+row)*DDF + seg*4);
    }
    __syncthreads();
    #pragma unroll
    for (int d4 = 0; d4 < 8; ++d4) {
      float4 wlo[4], whi[4];
      #pragma unroll
      for (int dd = 0; dd < 4; ++dd) {
        wlo[dd] = *(const float4*)(&Ws[(d4*4+dd)*256 + c0]);
        whi[dd] = *(const float4*)(&Ws[(d4*4+dd)*256 + c0 + 128]);
      }
      #pragma unroll
      for (int i = 0; i < 8; ++i) {
        float4 av = *(const float4*)(&As[(r0+i)*32 + d4*4]);
        float a0 = av.x, a1 = av.y, a2 = av.z, a3 = av.w;
        #define FMA8(aa, dd) \
          acc[i][0] = fmaf(aa, wlo[dd].x, acc[i][0]); \
          acc[i][1] = fmaf(aa, wlo[dd].y, acc[i][1]); \
          acc[i][2] = fmaf(aa, wlo[dd].z, acc[i][2]); \
          acc[i][3] = fmaf(aa, wlo[dd].w, acc[i][3]); \
          acc[i][4] = fmaf(aa, whi[dd].x, acc[i][4]); \
          acc[i][5] = fmaf(aa, whi[dd].y, acc[i][5]); \
          acc[i][6] = fmaf(aa, whi[dd].z, acc[i][6]); \
          acc[i][7] = fmaf(aa, whi[dd].w, acc[i][7]);
        FMA8(a0, 0) FMA8(a1, 1) FMA8(a2, 2) FMA8(a3, 3)
        #undef FMA8
      }
    }
    __syncthreads();
  }
  // + b1, write h1, per-block column stats (deterministic tree)
  float4 blo = *(const float4*)(b1 + c0);
  float4 bhi = *(const float4*)(b1 + c0 + 128);
  float s1[8] = {0,0,0,0,0,0,0,0};
  float s2[8] = {0,0,0,0,0,0,0,0};
  #pragma unroll
  for (int i = 0; i < 8; ++i) {
    acc[i][0]+=blo.x; acc[i][1]+=blo.y; acc[i][2]+=blo.z; acc[i][3]+=blo.w;
    acc[i][4]+=bhi.x; acc[i][5]+=bhi.y; acc[i][6]+=bhi.z; acc[i][7]+=bhi.w;
    #pragma unroll
    for (int j = 0; j < 8; ++j) { float v = acc[i][j]; s1[j] += v; s2[j] += v*v; }
    *(float4*)(h1 + (n0 + r0 + i)*DDF + c0) =
        make_float4(acc[i][0],acc[i][1],acc[i][2],acc[i][3]);
    *(float4*)(h1 + (n0 + r0 + i)*DDF + c0 + 128) =
        make_float4(acc[i][4],acc[i][5],acc[i][6],acc[i][7]);
  }
  const int rg = t >> 5;
  *(float4*)(&red[rg*256 + c0])       = make_float4(s1[0],s1[1],s1[2],s1[3]);
  *(float4*)(&red[rg*256 + c0 + 128]) = make_float4(s1[4],s1[5],s1[6],s1[7]);
  __syncthreads();
  float tot = 0.f;
  #pragma unroll
  for (int g = 0; g < 8; ++g) tot += red[g*256 + t];
  psum[blockIdx.x*256 + t] = tot;
  __syncthreads();
  *(float4*)(&red[rg*256 + c0])       = make_float4(s2[0],s2[1],s2[2],s2[3]);
  *(float4*)(&red[rg*256 + c0 + 128]) = make_float4(s2[4],s2[5],s2[6],s2[7]);
  __syncthreads();
  tot = 0.f;
  #pragma unroll
  for (int g = 0; g < 8; ++g) tot += red[g*256 + t];
  psq[blockIdx.x*256 + t] = tot;
}

// ============ K2a: reduce 2048 partial rows -> 16x256 ============
__global__ __launch_bounds__(256) void k2a(const float* __restrict__ psum,
                                           const float* __restrict__ psq,
                                           float* __restrict__ tmp)
{
  int g = blockIdx.x & 7;
  const float* src = (blockIdx.x < 8) ? psum : psq;
  float acc = 0.f;
  #pragma unroll 8
  for (int r = 0; r < 256; ++r) acc += src[(g*256 + r)*256 + threadIdx.x];
  tmp[blockIdx.x*256 + threadIdx.x] = acc;
}

// ============ K2b: finalize BN scale/shift ============
__global__ __launch_bounds__(256) void k2b(const float* __restrict__ tmp,
    const float* __restrict__ gam, const float* __restrict__ bet,
    float* __restrict__ scale, float* __restrict__ shift)
{
  int d = threadIdx.x;
  float s1 = 0.f, s2 = 0.f;
  #pragma unroll
  for (int g = 0; g < 8; ++g) { s1 += tmp[g*256+d]; s2 += tmp[(8+g)*256+d]; }
  float mu  = s1 * (1.0f / (float)NN);
  float var = s2 * (1.0f / (float)NN) - mu*mu;
  float inv = 1.0f / sqrtf(var + 1e-5f);
  float sc = gam[d] * inv;
  scale[d] = sc;
  shift[d] = bet[d] - mu*sc;
}

// ============ K2c: Un = U / max(||U||,1e-12) ============
__global__ __launch_bounds__(64) void k2c(const float* __restrict__ U,
                                          float* __restrict__ Un)
{
  int k = blockIdx.x, l = threadIdx.x;
  float4 u = *(const float4*)(U + k*256 + l*4);
  float ss = u.x*u.x + u.y*u.y + u.z*u.z + u.w*u.w;
  #pragma unroll
  for (int off = 32; off >= 1; off >>= 1) ss += __shfl_xor(ss, off);
  float inv = 1.0f / fmaxf(sqrtf(ss), 1e-12f);
  *(float4*)(Un + k*256 + l*4) = make_float4(u.x*inv, u.y*inv, u.z*inv, u.w*inv);
}

// ============ K3: per-graph BN+lrelu+GEMM2+softmax+std-filter ============
// 4 waves/block, one graph per wave. Lane owns rows l and l+64 fully in regs.
// W2/b2 are wave-uniform -> scalar loads (no LDS for B operand).
__global__ __launch_bounds__(256) void k3_gemm2(
    const float* __restrict__ h1, const float* __restrict__ W2,
    const float* __restrict__ b2, const float* __restrict__ scale,
    const float* __restrict__ shift, float* __restrict__ s_out,
    float* __restrict__ sf_out)
{
  __shared__ float ylds[4][128*32];   // 64 KB, per-wave y tile (XOR-swizzled f4 slots)
  const int t = threadIdx.x;
  const int w = t >> 6, l = t & 63;
  const int b = blockIdx.x*4 + w;
  float* my = ylds[w];

  float acc0[32], acc1[32];
  #pragma unroll
  for (int k = 0; k < 32; ++k) { acc0[k] = 0.f; acc1[k] = 0.f; }

  const int slot  = l & 7;
  const int rbase = l >> 3;
  const int lx7   = l & 7;

  for (int ch = 0; ch < 8; ++ch) {
    const int dbase = ch*32 + slot*4;
    const float4 sc = *(const float4*)(scale + dbase);
    const float4 sh = *(const float4*)(shift + dbase);
    #pragma unroll
    for (int i = 0; i < 16; ++i) {
      int row = rbase + i*8;
      float4 v = *(const float4*)(h1 + (b*MMN + row)*DDF + dbase);
      float y0 = fmaf(v.x, sc.x, sh.x); y0 = y0 > 0.f ? y0 : 0.01f*y0;
      float y1 = fmaf(v.y, sc.y, sh.y); y1 = y1 > 0.f ? y1 : 0.01f*y1;
      float y2 = fmaf(v.z, sc.z, sh.z); y2 = y2 > 0.f ? y2 : 0.01f*y2;
      float y3 = fmaf(v.w, sc.w, sh.w); y3 = y3 > 0.f ? y3 : 0.01f*y3;
      *(float4*)(&my[row*32 + (slot ^ (row & 7))*4]) = make_float4(y0,y1,y2,y3);
    }
    // wave-private region: in-wave LDS ordering suffices, no barrier needed
    #pragma unroll
    for (int d4 = 0; d4 < 8; ++d4) {
      float4 ya = *(const float4*)(&my[ l     *32 + ((d4 ^ lx7))*4]);
      float4 yb = *(const float4*)(&my[(l+64)*32 + ((d4 ^ lx7))*4]);
      #pragma unroll
      for (int dd = 0; dd < 4; ++dd) {
        const float* w2r = W2 + (ch*32 + d4*4 + dd)*KKC;
        float a = (dd==0?ya.x: dd==1?ya.y: dd==2?ya.z: ya.w);
        float c = (dd==0?yb.x: dd==1?yb.y: dd==2?yb.z: yb.w);
        #pragma unroll
        for (int k = 0; k < 32; ++k) {
          float wv = w2r[k];
          acc0[k] = fmaf(a, wv, acc0[k]);
          acc1[k] = fmaf(c, wv, acc1[k]);
        }
      }
    }
  }
  #pragma unroll
  for (int k = 0; k < 32; ++k) {
    float bb = b2[k];
    acc0[k] = (acc0[k] + bb) * 10.0f;   // /T1
    acc1[k] = (acc1[k] + bb) * 10.0f;
  }
  float thr0, thr1;
  {
    float* a = acc0; float* thrp = &thr0;
    #pragma unroll
    for (int r = 0; r < 2; ++r) {
      float m = a[0];
      #pragma unroll
      for (int k = 1; k < 32; ++k) m = fmaxf(m, a[k]);
      float sum = 0.f;
      #pragma unroll
      for (int k = 0; k < 32; ++k) { float e = expf(a[k]-m); a[k] = e; sum += e; }
      float inv = 1.0f/sum;
      float ssum = 0.f;
      #pragma unroll
      for (int k = 0; k < 32; ++k) { a[k] *= inv; ssum += a[k]; }
      float mean = ssum * (1.0f/32.0f);
      float var = 0.f;
      #pragma unroll
      for (int k = 0; k < 32; ++k) { float d = a[k]-mean; var += d*d; }
      *thrp = sqrtf(var * (1.0f/31.0f)) + 0.03125f;  // std(ddof=1) + 1/K
      a = acc1; thrp = &thr1;
    }
  }
  // stage s (swizzled) -> coalesced global write
  #pragma unroll
  for (int q = 0; q < 8; ++q) {
    *(float4*)(&my[ l     *32 + (q ^ lx7)*4]) =
        make_float4(acc0[q*4],acc0[q*4+1],acc0[q*4+2],acc0[q*4+3]);
    *(float4*)(&my[(l+64)*32 + (q ^ lx7)*4]) =
        make_float4(acc1[q*4],acc1[q*4+1],acc1[q*4+2],acc1[q*4+3]);
  }
  #pragma unroll
  for (int i = 0; i < 16; ++i) {
    int fid = l + i*64;
    int row = fid >> 3, q = fid & 7;
    *(float4*)(s_out + b*4096 + fid*4) =
        *(const float4*)(&my[row*32 + (q ^ (row & 7))*4]);
  }
  // filter -> sf, stage, write to ws
  #pragma unroll
  for (int k = 0; k < 32; ++k) {
    acc0[k] = acc0[k] > thr0 ? acc0[k] : 0.f;
    acc1[k] = acc1[k] > thr1 ? acc1[k] : 0.f;
  }
  #pragma unroll
  for (int q = 0; q < 8; ++q) {
    *(float4*)(&my[ l     *32 + (q ^ lx7)*4]) =
        make_float4(acc0[q*4],acc0[q*4+1],acc0[q*4+2],acc0[q*4+3]);
    *(float4*)(&my[(l+64)*32 + (q ^ lx7)*4]) =
        make_float4(acc1[q*4],acc1[q*4+1],acc1[q*4+2],acc1[q*4+3]);
  }
  #pragma unroll
  for (int i = 0; i < 16; ++i) {
    int fid = l + i*64;
    int row = fid >> 3, q = fid & 7;
    *(float4*)(sf_out + b*4096 + fid*4) =
        *(const float4*)(&my[row*32 + (q ^ (row & 7))*4]);
  }
}

// ============ K4: per-graph pooling + h_dense/h_flat/mask + hn + p ============
__global__ __launch_bounds__(256) void k4_pool(
    const float* __restrict__ sf, const float* __restrict__ z,
    const float* __restrict__ Un, float* __restrict__ c_out,
    float* __restrict__ hdense, float* __restrict__ hflat,
    float* __restrict__ p_out, float* __restrict__ mask_out)
{
  __shared__ __align__(16) char smem[66048];
  __shared__ float redp[8*32];
  __shared__ float cred[32];
  float* sflds = (float*)smem;              // phase A: [128][32]
  float* zlds  = (float*)(smem + 16384);    // phase A: [32][256]
  float* hnlds = (float*)smem;              // phase B: [32][260]
  float* unlds = (float*)(smem + 33280);    // phase B: [32][256]

  const int t = threadIdx.x;
  const int w = t >> 6, l = t & 63;
  const int b = blockIdx.x;

  #pragma unroll
  for (int i = 0; i < 4; ++i) {
    int fid = t + i*256;
    *(float4*)(&sflds[fid*4]) = *(const float4*)(sf + b*4096 + fid*4);
  }
  __syncthreads();
  {
    int k = t & 31, mg = t >> 5;
    float p = 0.f;
    #pragma unroll
    for (int m = 0; m < 16; ++m) p += sflds[(mg*16+m)*32 + k];
    redp[mg*32 + k] = p;
  }
  __syncthreads();
  if (t < 32) {
    float c = 0.f;
    #pragma unroll
    for (int g = 0; g < 8; ++g) c += redp[g*32 + t];
    cred[t] = c;
    c_out[b*32 + t] = c;
  }
  __syncthreads();

  // pooling: wave w owns k=w*8..+7; lane owns d=l*4..+3
  float acc[8][4];
  #pragma unroll
  for (int kk = 0; kk < 8; ++kk)
    #pragma unroll
    for (int j = 0; j < 4; ++j) acc[kk][j] = 0.f;

  for (int ch = 0; ch < 4; ++ch) {
    #pragma unroll
    for (int i = 0; i < 8; ++i) {
      int fid = t + i*256;
      *(float4*)(&zlds[fid*4]) =
          *(const float4*)(z + (b*128 + ch*32)*256 + fid*4);
    }
    __syncthreads();
    #pragma unroll
    for (int mm = 0; mm < 32; ++mm) {
      float4 zv = *(const float4*)(&zlds[mm*256 + l*4]);
      float4 sa = *(const float4*)(&sflds[(ch*32+mm)*32 + w*8]);
      float4 sb = *(const float4*)(&sflds[(ch*32+mm)*32 + w*8 + 4]);
      float sv[8] = {sa.x,sa.y,sa.z,sa.w,sb.x,sb.y,sb.z,sb.w};
      #pragma unroll
      for (int kk = 0; kk < 8; ++kk) {
        acc[kk][0] = fmaf(sv[kk], zv.x, acc[kk][0]);
        acc[kk][1] = fmaf(sv[kk], zv.y, acc[kk][1]);
        acc[kk][2] = fmaf(sv[kk], zv.z, acc[kk][2]);
        acc[kk][3] = fmaf(sv[kk], zv.w, acc[kk][3]);
      }
    }
    __syncthreads();
  }
  // normalize weights, sums, mask, writes
  float asum[8], qsum[8], mkarr[8];
  #pragma unroll
  for (int kk = 0; kk < 8; ++kk) {
    float wnv = 1.0f / fmaxf(cred[w*8+kk], 1e-12f);
    acc[kk][0]*=wnv; acc[kk][1]*=wnv; acc[kk][2]*=wnv; acc[kk][3]*=wnv;
    asum[kk] = fabsf(acc[kk][0])+fabsf(acc[kk][1])+fabsf(acc[kk][2])+fabsf(acc[kk][3]);
    qsum[kk] = acc[kk][0]*acc[kk][0]+acc[kk][1]*acc[kk][1]
             + acc[kk][2]*acc[kk][2]+acc[kk][3]*acc[kk][3];
  }
  #pragma unroll
  for (int kk = 0; kk < 8; ++kk) {
    float a = asum[kk], q = qsum[kk];
    #pragma unroll
    for (int off = 1; off < 64; off <<= 1) {
      a += __shfl_xor(a, off); q += __shfl_xor(q, off);
    }
    asum[kk] = a; qsum[kk] = q;
  }
  #pragma unroll
  for (int kk = 0; kk < 8; ++kk) {
    int krow = b*32 + w*8 + kk;
    float mk = asum[kk] > 0.f ? 1.0f : 0.0f;
    mkarr[kk] = mk;
    float inv = 1.0f / fmaxf(sqrtf(qsum[kk]) * mk, 1e-12f);
    float h0=acc[kk][0], h1v=acc[kk][1], h2=acc[kk][2], h3=acc[kk][3];
    *(float4*)(hdense + krow*256 + l*4) = make_float4(h0,h1v,h2,h3);
    float f0=h0*mk, f1=h1v*mk, f2=h2*mk, f3=h3*mk;
    *(float4*)(hflat + krow*256 + l*4) = make_float4(f0,f1,f2,f3);
    acc[kk][0]=f0*inv; acc[kk][1]=f1*inv; acc[kk][2]=f2*inv; acc[kk][3]=f3*inv;
  }
  if (l == 0) {
    #pragma unroll
    for (int kk = 0; kk < 8; ++kk) mask_out[b*32 + w*8 + kk] = mkarr[kk];
  }
  // phase B: p = hn @ Un^T  (smem reuse is safe: all reads done before last barrier)
  #pragma unroll
  for (int kk = 0; kk < 8; ++kk)
    *(float4*)(&hnlds[(w*8+kk)*260 + l*4]) =
        make_float4(acc[kk][0],acc[kk][1],acc[kk][2],acc[kk][3]);
  #pragma unroll
  for (int i = 0; i < 8; ++i) {
    int fid = t + i*256;
    *(float4*)(&unlds[fid*4]) = *(const float4*)(Un + fid*4);
  }
  __syncthreads();
  {
    const int k = t & 31, k2 = (t >> 5) * 4;
    float p0=0.f, p1=0.f, p2=0.f, p3=0.f;
    #pragma unroll 8
    for (int d4 = 0; d4 < 64; ++d4) {
      float4 hv = *(const float4*)(&hnlds[k*260 + d4*4]);
      float4 u0 = *(const float4*)(&unlds[(k2+0)*256 + d4*4]);
      float4 u1 = *(const float4*)(&unlds[(k2+1)*256 + d4*4]);
      float4 u2 = *(const float4*)(&unlds[(k2+2)*256 + d4*4]);
      float4 u3 = *(const float4*)(&unlds[(k2+3)*256 + d4*4]);
      p0 = fmaf(hv.x,u0.x,fmaf(hv.y,u0.y,fmaf(hv.z,u0.z,fmaf(hv.w,u0.w,p0))));
      p1 = fmaf(hv.x,u1.x,fmaf(hv.y,u1.y,fmaf(hv.z,u1.z,fmaf(hv.w,u1.w,p1))));
      p2 = fmaf(hv.x,u2.x,fmaf(hv.y,u2.y,fmaf(hv.z,u2.z,fmaf(hv.w,u2.w,p2))));
      p3 = fmaf(hv.x,u3.x,fmaf(hv.y,u3.y,fmaf(hv.z,u3.z,fmaf(hv.w,u3.w,p3))));
    }
    *(float4*)(p_out + (b*32 + k)*32 + k2) = make_float4(p0,p1,p2,p3);
  }
}

// ============ K5a: partial sums of h_dense over b ============
__global__ __launch_bounds__(256) void k5a(const float* __restrict__ hdense,
                                           float* __restrict__ part)
{
  int k = blockIdx.x & 31, seg = blockIdx.x >> 5;
  int t = threadIdx.x;
  float s = 0.f;
  #pragma unroll 4
  for (int i = 0; i < 128; ++i) {
    int b = seg*128 + i;
    s += hdense[(b*32 + k)*256 + t];
  }
  part[blockIdx.x*256 + t] = s;
}

// ============ K5b: sizes (reshape semantics!) + centroids + U_new ============
__global__ __launch_bounds__(256) void k5b(const float* __restrict__ part,
    const float* __restrict__ maskf, const float* __restrict__ U,
    float* __restrict__ Unew)
{
  __shared__ float r4[4];
  int k = blockIdx.x, t = threadIdx.x;
  // sizes[k] = sum of sub_mask.flat[k*1024 .. k*1024+1024)  (reshape, not transpose)
  float4 mv = *(const float4*)(maskf + k*1024 + t*4);
  float m4 = mv.x + mv.y + mv.z + mv.w;
  #pragma unroll
  for (int off = 1; off < 64; off <<= 1) m4 += __shfl_xor(m4, off);
  if ((t & 63) == 0) r4[t >> 6] = m4;
  __syncthreads();
  float sizes = r4[0] + r4[1] + r4[2] + r4[3];
  float csum = 0.f;
  #pragma unroll
  for (int g = 0; g < 8; ++g) csum += part[(g*32 + k)*256 + t];
  float cent = csum / (sizes + 1e-10f);
  Unew[k*256 + t] = 0.99f * U[k*256 + t] + 0.01f * cent;
}

// ============ K6: p_hat diag-embed ============
__global__ __launch_bounds__(256) void k6_phat(const float* __restrict__ c,
                                               float* __restrict__ phat)
{
  int idx = blockIdx.x*256 + threadIdx.x;     // < 1048576
  int b = idx >> 10, rr = idx & 1023, k1 = rr >> 5, k2 = rr & 31;
  float v = 0.f;
  if (k1 == k2) { float cc = c[b*32 + k1]; v = cc / (cc + 1e-12f); }
  phat[idx] = v;
}

// ============ K7: z_dense = z copy, g passthrough (runs last: frees h1 region) ============
__global__ __launch_bounds__(256) void k7_copy(const float* __restrict__ z,
    const float* __restrict__ g, float* __restrict__ zd, float* __restrict__ gout)
{
  int idx = blockIdx.x*256 + threadIdx.x;     // float4 index
  if (idx < 8388608) {
    *(float4*)(zd + idx*4) = *(const float4*)(z + idx*4);
  } else {
    int j = idx - 8388608;                    // < 65536
    *(float4*)(gout + j*4) = *(const float4*)(g + j*4);
  }
}

extern "C" void kernel_launch(void* const* d_in, const int* in_sizes, int n_in,
                              void* d_out, int out_size, void* d_ws, size_t ws_size,
                              hipStream_t stream)
{
  const float* z   = (const float*)d_in[0];
  const float* g   = (const float*)d_in[1];
  // d_in[2] = batch (arange//M, graphs contiguous) — layout exploited directly
  const float* W1  = (const float*)d_in[3];
  const float* b1  = (const float*)d_in[4];
  const float* gam = (const float*)d_in[5];
  const float* bet = (const float*)d_in[6];
  const float* W2  = (const float*)d_in[7];
  const float* b2  = (const float*)d_in[8];
  const float* U   = (const float*)d_in[9];
  float* out = (float*)d_out;
  float* ws  = (float*)d_ws;

  float* h1 = out + OFF_ZD;   // stash h1 in z_dense region; K7 overwrites it last

  k1_gemm1<<<2048, 256, 0, stream>>>(z, W1, b1, h1, ws+WS_PSUM, ws+WS_PSQ);
  k2a<<<16, 256, 0, stream>>>(ws+WS_PSUM, ws+WS_PSQ, ws+WS_TMP);
  k2b<<<1, 256, 0, stream>>>(ws+WS_TMP, gam, bet, ws+WS_SCALE, ws+WS_SHIFT);
  k2c<<<32, 64, 0, stream>>>(U, ws+WS_UN);
  k3_gemm2<<<256, 256, 0, stream>>>(h1, W2, b2, ws+WS_SCALE, ws+WS_SHIFT,
                                    out+OFF_S, ws+WS_SF);
  k4_pool<<<1024, 256, 0, stream>>>(ws+WS_SF, z, ws+WS_UN, ws+WS_C,
                                    out+OFF_HDENSE, out+OFF_HFLAT,
                                    out+OFF_P, out+OFF_MASK);
  k5a<<<256, 256, 0, stream>>>(out+OFF_HDENSE, ws+WS_PART);
  k5b<<<32, 256, 0, stream>>>(ws+WS_PART, out+OFF_MASK, U, out+OFF_UNEW);
  k6_phat<<<4096, 256, 0, stream>>>(ws+WS_C, out+OFF_PHAT);
  k7_copy<<<33024, 256, 0, stream>>>(z, g, out+OFF_ZD, out+OFF_G);
}

// Round 2
// 356.608 us; speedup vs baseline: 1.3393x; 1.3393x over previous
//
#include <hip/hip_runtime.h>
#include <math.h>

#define NN 131072
#define BBG 1024
#define MMN 128
#define DDF 256
#define KKC 32

// ---- d_out offsets (floats), concatenated in reference return order ----
#define OFF_S      0
#define OFF_HFLAT  4194304
#define OFF_HDENSE 12582912
#define OFF_P      20971520
#define OFF_PHAT   22020096
#define OFF_ZD     23068672
#define OFF_G      56623104
#define OFF_MASK   56885248
#define OFF_UNEW   56918016

// ---- ws offsets (floats) ----
#define WS_PSUM  0          // [1024][256]
#define WS_PSQ   524288     // [1024][256]
#define WS_TMP   1048576    // [16][256]
#define WS_SCALE 1052672    // [256]
#define WS_SHIFT 1052928    // [256]
#define WS_UN    1053184    // [32][256]
#define WS_SF    1061376    // [N][32]
#define WS_C     5255680    // [B][32]
#define WS_PART  5288448    // [8*32][256]

typedef __attribute__((ext_vector_type(8))) short short8;
typedef __attribute__((ext_vector_type(4))) float f32x4;

__device__ __forceinline__ unsigned short f2bf(float x) {
  unsigned u = __float_as_uint(x);
  u += 0x7fffu + ((u >> 16) & 1u);
  return (unsigned short)(u >> 16);
}
__device__ __forceinline__ float bf2f(unsigned short h) {
  return __uint_as_float(((unsigned)h) << 16);
}
__device__ __forceinline__ void gload_lds16(const void* g, void* l) {
  __builtin_amdgcn_global_load_lds(
      (const __attribute__((address_space(1))) unsigned int*)g,
      (__attribute__((address_space(3))) unsigned int*)l, 16, 0, 0);
}

// ============ K0: W1 -> blocked bf16 hi/lo, layout [kstep][g][n][j] ============
// k = kstep*32 + g*8 + j ; element holds W1[k][n]. 8192 threads.
__global__ __launch_bounds__(256) void k0_prep(const float* __restrict__ W1,
    unsigned short* __restrict__ preh, unsigned short* __restrict__ prel)
{
  int tid = blockIdx.x * 256 + threadIdx.x;   // < 8192
  int n = tid & 255, kq = tid >> 8;           // kq in [0,32): k = kq*8 + j
  short8 hv, lv;
  #pragma unroll
  for (int j = 0; j < 8; ++j) {
    float v = W1[(kq * 8 + j) * DDF + n];
    unsigned short hb = f2bf(v);
    hv[j] = (short)hb;
    lv[j] = (short)f2bf(v - bf2f(hb));
  }
  int base = (kq >> 2) * 8192 + (kq & 3) * 2048 + n * 8;
  *(short8*)(preh + base) = hv;
  *(short8*)(prel + base) = lv;
}

// ============ K1: h1 = z@W1 + b1 via bf16x2-split MFMA + column stats ============
// 1024 blocks x 512 thr (8 waves, 2x4 grid, 64x64 per wave). BK=32, 8 K-steps.
__global__ __launch_bounds__(512) void k1_gemm1(
    const float* __restrict__ z, const unsigned short* __restrict__ preh,
    const unsigned short* __restrict__ prel, const float* __restrict__ b1,
    float* __restrict__ h1, float* __restrict__ psum, float* __restrict__ psq)
{
  __shared__ __attribute__((aligned(16))) unsigned short Ah[128 * 40]; // pad 32->40
  __shared__ __attribute__((aligned(16))) unsigned short Al[128 * 40];
  __shared__ __attribute__((aligned(16))) unsigned short Bh[4 * 256 * 8]; // [g][n][8]
  __shared__ __attribute__((aligned(16))) unsigned short Bl[4 * 256 * 8];

  const int t = threadIdx.x;
  const int l = t & 63;
  const int w = t >> 6;          // wave 0..7
  const int wr = w >> 2;         // 0..1  (row half)
  const int wc = w & 3;          // 0..3  (col quarter)
  const int lg = l >> 4;         // lane group 0..3 (k-chunk / row sub)
  const int l16 = l & 15;
  const int n0 = blockIdx.x * 128;

  f32x4 acc[4][4];
  #pragma unroll
  for (int i = 0; i < 4; ++i)
    #pragma unroll
    for (int j = 0; j < 4; ++j) acc[i][j] = (f32x4)0.0f;

  const int arow = t >> 2, ac = t & 3;          // A staging: row, 4-float chunk
  const float* zrow = z + (size_t)(n0 + arow) * DDF;

  for (int ks = 0; ks < 8; ++ks) {
    __syncthreads();   // prior-step LDS reads complete before overwrite
    // ---- B staging: global_load_lds 16B x4 per wave (hi+lo) ----
    {
      const unsigned short* gh = preh + ks * 8192 + w * 1024 + l * 8;
      const unsigned short* gl = prel + ks * 8192 + w * 1024 + l * 8;
      gload_lds16(gh,        &Bh[w * 1024]);
      gload_lds16(gh + 512,  &Bh[w * 1024 + 512]);
      gload_lds16(gl,        &Bl[w * 1024]);
      gload_lds16(gl + 512,  &Bl[w * 1024 + 512]);
    }
    // ---- A staging: load f32, split to bf16 hi/lo, ds_write ----
    {
      float4 za = *(const float4*)(zrow + ks * 32 + ac * 4);
      float4 zb = *(const float4*)(zrow + ks * 32 + 16 + ac * 4);
      unsigned short h0 = f2bf(za.x), h1v = f2bf(za.y), h2 = f2bf(za.z), h3 = f2bf(za.w);
      unsigned short g0 = f2bf(zb.x), g1 = f2bf(zb.y), g2 = f2bf(zb.z), g3 = f2bf(zb.w);
      uint2 hA = make_uint2((unsigned)h0 | ((unsigned)h1v << 16),
                            (unsigned)h2 | ((unsigned)h3 << 16));
      uint2 hB = make_uint2((unsigned)g0 | ((unsigned)g1 << 16),
                            (unsigned)g2 | ((unsigned)g3 << 16));
      uint2 lA = make_uint2((unsigned)f2bf(za.x - bf2f(h0)) | ((unsigned)f2bf(za.y - bf2f(h1v)) << 16),
                            (unsigned)f2bf(za.z - bf2f(h2)) | ((unsigned)f2bf(za.w - bf2f(h3)) << 16));
      uint2 lB = make_uint2((unsigned)f2bf(zb.x - bf2f(g0)) | ((unsigned)f2bf(zb.y - bf2f(g1)) << 16),
                            (unsigned)f2bf(zb.z - bf2f(g2)) | ((unsigned)f2bf(zb.w - bf2f(g3)) << 16));
      *(uint2*)(&Ah[arow * 40 + ac * 4])      = hA;
      *(uint2*)(&Ah[arow * 40 + 16 + ac * 4]) = hB;
      *(uint2*)(&Al[arow * 40 + ac * 4])      = lA;
      *(uint2*)(&Al[arow * 40 + 16 + ac * 4]) = lB;
    }
    __syncthreads();
    // ---- fragments + 4-term MFMA ----
    short8 bfh[4], bfl[4];
    #pragma unroll
    for (int nf = 0; nf < 4; ++nf) {
      int nb = wc * 64 + nf * 16 + l16;
      bfh[nf] = *(const short8*)(&Bh[lg * 2048 + nb * 8]);
      bfl[nf] = *(const short8*)(&Bl[lg * 2048 + nb * 8]);
    }
    #pragma unroll
    for (int mf = 0; mf < 4; ++mf) {
      int ar = wr * 64 + mf * 16 + l16;
      short8 afh = *(const short8*)(&Ah[ar * 40 + lg * 8]);
      short8 afl = *(const short8*)(&Al[ar * 40 + lg * 8]);
      #pragma unroll
      for (int nf = 0; nf < 4; ++nf) {
        acc[mf][nf] = __builtin_amdgcn_mfma_f32_16x16x32_bf16(afh, bfh[nf], acc[mf][nf], 0, 0, 0);
        acc[mf][nf] = __builtin_amdgcn_mfma_f32_16x16x32_bf16(afh, bfl[nf], acc[mf][nf], 0, 0, 0);
        acc[mf][nf] = __builtin_amdgcn_mfma_f32_16x16x32_bf16(afl, bfh[nf], acc[mf][nf], 0, 0, 0);
        acc[mf][nf] = __builtin_amdgcn_mfma_f32_16x16x32_bf16(afl, bfl[nf], acc[mf][nf], 0, 0, 0);
      }
    }
  }

  // ---- epilogue: +b1, write h1 (C/D layout: col=l&15, row=(l>>4)*4+j), stats ----
  float s1[4] = {0, 0, 0, 0}, s2[4] = {0, 0, 0, 0};
  #pragma unroll
  for (int nf = 0; nf < 4; ++nf) {
    int c = wc * 64 + nf * 16 + l16;
    float bb = b1[c];
    #pragma unroll
    for (int mf = 0; mf < 4; ++mf) {
      int rbase = n0 + wr * 64 + mf * 16 + lg * 4;
      #pragma unroll
      for (int j = 0; j < 4; ++j) {
        float v = acc[mf][nf][j] + bb;
        s1[nf] += v; s2[nf] += v * v;
        h1[(size_t)(rbase + j) * DDF + c] = v;
      }
    }
  }
  // combine the 4 lane-groups (row sub-blocks) -> every lane holds 64-row col sums
  #pragma unroll
  for (int nf = 0; nf < 4; ++nf) {
    s1[nf] += __shfl_xor(s1[nf], 16); s1[nf] += __shfl_xor(s1[nf], 32);
    s2[nf] += __shfl_xor(s2[nf], 16); s2[nf] += __shfl_xor(s2[nf], 32);
  }
  __syncthreads();                // done with MFMA LDS; reuse Ah/Al as f32 buffers
  float* red1 = (float*)Ah;       // [2][256]
  float* red2 = (float*)Al;       // [2][256]
  if (l < 16) {
    #pragma unroll
    for (int nf = 0; nf < 4; ++nf) {
      red1[wr * 256 + wc * 64 + nf * 16 + l] = s1[nf];
      red2[wr * 256 + wc * 64 + nf * 16 + l] = s2[nf];
    }
  }
  __syncthreads();
  if (t < 256) {
    psum[blockIdx.x * 256 + t] = red1[t] + red1[256 + t];
    psq [blockIdx.x * 256 + t] = red2[t] + red2[256 + t];
  }
}

// ============ K2a: reduce 1024 partial rows -> 16x256 ============
__global__ __launch_bounds__(256) void k2a(const float* __restrict__ psum,
                                           const float* __restrict__ psq,
                                           float* __restrict__ tmp)
{
  int g = blockIdx.x & 7;
  const float* src = (blockIdx.x < 8) ? psum : psq;
  float acc = 0.f;
  #pragma unroll 8
  for (int r = 0; r < 128; ++r) acc += src[(g * 128 + r) * 256 + threadIdx.x];
  tmp[blockIdx.x * 256 + threadIdx.x] = acc;
}

// ============ K2b: finalize BN scale/shift ============
__global__ __launch_bounds__(256) void k2b(const float* __restrict__ tmp,
    const float* __restrict__ gam, const float* __restrict__ bet,
    float* __restrict__ scale, float* __restrict__ shift)
{
  int d = threadIdx.x;
  float s1 = 0.f, s2 = 0.f;
  #pragma unroll
  for (int g = 0; g < 8; ++g) { s1 += tmp[g*256+d]; s2 += tmp[(8+g)*256+d]; }
  float mu  = s1 * (1.0f / (float)NN);
  float var = s2 * (1.0f / (float)NN) - mu*mu;
  float inv = 1.0f / sqrtf(var + 1e-5f);
  float sc = gam[d] * inv;
  scale[d] = sc;
  shift[d] = bet[d] - mu*sc;
}

// ============ K2c: Un = U / max(||U||,1e-12) ============
__global__ __launch_bounds__(64) void k2c(const float* __restrict__ U,
                                          float* __restrict__ Un)
{
  int k = blockIdx.x, l = threadIdx.x;
  float4 u = *(const float4*)(U + k*256 + l*4);
  float ss = u.x*u.x + u.y*u.y + u.z*u.z + u.w*u.w;
  #pragma unroll
  for (int off = 32; off >= 1; off >>= 1) ss += __shfl_xor(ss, off);
  float inv = 1.0f / fmaxf(sqrtf(ss), 1e-12f);
  *(float4*)(Un + k*256 + l*4) = make_float4(u.x*inv, u.y*inv, u.z*inv, u.w*inv);
}

// ============ K3: per-graph BN+lrelu+GEMM2+softmax+std-filter ============
__global__ __launch_bounds__(256) void k3_gemm2(
    const float* __restrict__ h1, const float* __restrict__ W2,
    const float* __restrict__ b2, const float* __restrict__ scale,
    const float* __restrict__ shift, float* __restrict__ s_out,
    float* __restrict__ sf_out)
{
  __shared__ float ylds[4][128*32];   // 64 KB, per-wave y tile (XOR-swizzled f4 slots)
  const int t = threadIdx.x;
  const int w = t >> 6, l = t & 63;
  const int b = blockIdx.x*4 + w;
  float* my = ylds[w];

  float acc0[32], acc1[32];
  #pragma unroll
  for (int k = 0; k < 32; ++k) { acc0[k] = 0.f; acc1[k] = 0.f; }

  const int slot  = l & 7;
  const int rbase = l >> 3;
  const int lx7   = l & 7;

  for (int ch = 0; ch < 8; ++ch) {
    const int dbase = ch*32 + slot*4;
    const float4 sc = *(const float4*)(scale + dbase);
    const float4 sh = *(const float4*)(shift + dbase);
    #pragma unroll
    for (int i = 0; i < 16; ++i) {
      int row = rbase + i*8;
      float4 v = *(const float4*)(h1 + (size_t)(b*MMN + row)*DDF + dbase);
      float y0 = fmaf(v.x, sc.x, sh.x); y0 = y0 > 0.f ? y0 : 0.01f*y0;
      float y1 = fmaf(v.y, sc.y, sh.y); y1 = y1 > 0.f ? y1 : 0.01f*y1;
      float y2 = fmaf(v.z, sc.z, sh.z); y2 = y2 > 0.f ? y2 : 0.01f*y2;
      float y3 = fmaf(v.w, sc.w, sh.w); y3 = y3 > 0.f ? y3 : 0.01f*y3;
      *(float4*)(&my[row*32 + (slot ^ (row & 7))*4]) = make_float4(y0,y1,y2,y3);
    }
    #pragma unroll
    for (int d4 = 0; d4 < 8; ++d4) {
      float4 ya = *(const float4*)(&my[ l     *32 + ((d4 ^ lx7))*4]);
      float4 yb = *(const float4*)(&my[(l+64)*32 + ((d4 ^ lx7))*4]);
      #pragma unroll
      for (int dd = 0; dd < 4; ++dd) {
        const float* w2r = W2 + (ch*32 + d4*4 + dd)*KKC;
        float a = (dd==0?ya.x: dd==1?ya.y: dd==2?ya.z: ya.w);
        float c = (dd==0?yb.x: dd==1?yb.y: dd==2?yb.z: yb.w);
        #pragma unroll
        for (int k = 0; k < 32; ++k) {
          float wv = w2r[k];
          acc0[k] = fmaf(a, wv, acc0[k]);
          acc1[k] = fmaf(c, wv, acc1[k]);
        }
      }
    }
  }
  #pragma unroll
  for (int k = 0; k < 32; ++k) {
    float bb = b2[k];
    acc0[k] = (acc0[k] + bb) * 10.0f;
    acc1[k] = (acc1[k] + bb) * 10.0f;
  }
  float thr0, thr1;
  {
    float* a = acc0; float* thrp = &thr0;
    #pragma unroll
    for (int r = 0; r < 2; ++r) {
      float m = a[0];
      #pragma unroll
      for (int k = 1; k < 32; ++k) m = fmaxf(m, a[k]);
      float sum = 0.f;
      #pragma unroll
      for (int k = 0; k < 32; ++k) { float e = expf(a[k]-m); a[k] = e; sum += e; }
      float inv = 1.0f/sum;
      float ssum = 0.f;
      #pragma unroll
      for (int k = 0; k < 32; ++k) { a[k] *= inv; ssum += a[k]; }
      float mean = ssum * (1.0f/32.0f);
      float var = 0.f;
      #pragma unroll
      for (int k = 0; k < 32; ++k) { float d = a[k]-mean; var += d*d; }
      *thrp = sqrtf(var * (1.0f/31.0f)) + 0.03125f;
      a = acc1; thrp = &thr1;
    }
  }
  #pragma unroll
  for (int q = 0; q < 8; ++q) {
    *(float4*)(&my[ l     *32 + (q ^ lx7)*4]) =
        make_float4(acc0[q*4],acc0[q*4+1],acc0[q*4+2],acc0[q*4+3]);
    *(float4*)(&my[(l+64)*32 + (q ^ lx7)*4]) =
        make_float4(acc1[q*4],acc1[q*4+1],acc1[q*4+2],acc1[q*4+3]);
  }
  #pragma unroll
  for (int i = 0; i < 16; ++i) {
    int fid = l + i*64;
    int row = fid >> 3, q = fid & 7;
    *(float4*)(s_out + (size_t)b*4096 + fid*4) =
        *(const float4*)(&my[row*32 + (q ^ (row & 7))*4]);
  }
  #pragma unroll
  for (int k = 0; k < 32; ++k) {
    acc0[k] = acc0[k] > thr0 ? acc0[k] : 0.f;
    acc1[k] = acc1[k] > thr1 ? acc1[k] : 0.f;
  }
  #pragma unroll
  for (int q = 0; q < 8; ++q) {
    *(float4*)(&my[ l     *32 + (q ^ lx7)*4]) =
        make_float4(acc0[q*4],acc0[q*4+1],acc0[q*4+2],acc0[q*4+3]);
    *(float4*)(&my[(l+64)*32 + (q ^ lx7)*4]) =
        make_float4(acc1[q*4],acc1[q*4+1],acc1[q*4+2],acc1[q*4+3]);
  }
  #pragma unroll
  for (int i = 0; i < 16; ++i) {
    int fid = l + i*64;
    int row = fid >> 3, q = fid & 7;
    *(float4*)(sf_out + (size_t)b*4096 + fid*4) =
        *(const float4*)(&my[row*32 + (q ^ (row & 7))*4]);
  }
}

// ============ K4: per-graph pooling + h_dense/h_flat/mask + hn + p ============
__global__ __launch_bounds__(256) void k4_pool(
    const float* __restrict__ sf, const float* __restrict__ z,
    const float* __restrict__ Un, float* __restrict__ c_out,
    float* __restrict__ hdense, float* __restrict__ hflat,
    float* __restrict__ p_out, float* __restrict__ mask_out)
{
  __shared__ __align__(16) char smem[66048];
  __shared__ float redp[8*32];
  __shared__ float cred[32];
  float* sflds = (float*)smem;
  float* zlds  = (float*)(smem + 16384);
  float* hnlds = (float*)smem;
  float* unlds = (float*)(smem + 33280);

  const int t = threadIdx.x;
  const int w = t >> 6, l = t & 63;
  const int b = blockIdx.x;

  #pragma unroll
  for (int i = 0; i < 4; ++i) {
    int fid = t + i*256;
    *(float4*)(&sflds[fid*4]) = *(const float4*)(sf + (size_t)b*4096 + fid*4);
  }
  __syncthreads();
  {
    int k = t & 31, mg = t >> 5;
    float p = 0.f;
    #pragma unroll
    for (int m = 0; m < 16; ++m) p += sflds[(mg*16+m)*32 + k];
    redp[mg*32 + k] = p;
  }
  __syncthreads();
  if (t < 32) {
    float c = 0.f;
    #pragma unroll
    for (int g = 0; g < 8; ++g) c += redp[g*32 + t];
    cred[t] = c;
    c_out[b*32 + t] = c;
  }
  __syncthreads();

  float acc[8][4];
  #pragma unroll
  for (int kk = 0; kk < 8; ++kk)
    #pragma unroll
    for (int j = 0; j < 4; ++j) acc[kk][j] = 0.f;

  for (int ch = 0; ch < 4; ++ch) {
    #pragma unroll
    for (int i = 0; i < 8; ++i) {
      int fid = t + i*256;
      *(float4*)(&zlds[fid*4]) =
          *(const float4*)(z + (size_t)(b*128 + ch*32)*256 + fid*4);
    }
    __syncthreads();
    #pragma unroll
    for (int mm = 0; mm < 32; ++mm) {
      float4 zv = *(const float4*)(&zlds[mm*256 + l*4]);
      float4 sa = *(const float4*)(&sflds[(ch*32+mm)*32 + w*8]);
      float4 sb = *(const float4*)(&sflds[(ch*32+mm)*32 + w*8 + 4]);
      float sv[8] = {sa.x,sa.y,sa.z,sa.w,sb.x,sb.y,sb.z,sb.w};
      #pragma unroll
      for (int kk = 0; kk < 8; ++kk) {
        acc[kk][0] = fmaf(sv[kk], zv.x, acc[kk][0]);
        acc[kk][1] = fmaf(sv[kk], zv.y, acc[kk][1]);
        acc[kk][2] = fmaf(sv[kk], zv.z, acc[kk][2]);
        acc[kk][3] = fmaf(sv[kk], zv.w, acc[kk][3]);
      }
    }
    __syncthreads();
  }
  float asum[8], qsum[8], mkarr[8];
  #pragma unroll
  for (int kk = 0; kk < 8; ++kk) {
    float wnv = 1.0f / fmaxf(cred[w*8+kk], 1e-12f);
    acc[kk][0]*=wnv; acc[kk][1]*=wnv; acc[kk][2]*=wnv; acc[kk][3]*=wnv;
    asum[kk] = fabsf(acc[kk][0])+fabsf(acc[kk][1])+fabsf(acc[kk][2])+fabsf(acc[kk][3]);
    qsum[kk] = acc[kk][0]*acc[kk][0]+acc[kk][1]*acc[kk][1]
             + acc[kk][2]*acc[kk][2]+acc[kk][3]*acc[kk][3];
  }
  #pragma unroll
  for (int kk = 0; kk < 8; ++kk) {
    float a = asum[kk], q = qsum[kk];
    #pragma unroll
    for (int off = 1; off < 64; off <<= 1) {
      a += __shfl_xor(a, off); q += __shfl_xor(q, off);
    }
    asum[kk] = a; qsum[kk] = q;
  }
  #pragma unroll
  for (int kk = 0; kk < 8; ++kk) {
    int krow = b*32 + w*8 + kk;
    float mk = asum[kk] > 0.f ? 1.0f : 0.0f;
    mkarr[kk] = mk;
    float inv = 1.0f / fmaxf(sqrtf(qsum[kk]) * mk, 1e-12f);
    float h0=acc[kk][0], h1v=acc[kk][1], h2=acc[kk][2], h3=acc[kk][3];
    *(float4*)(hdense + (size_t)krow*256 + l*4) = make_float4(h0,h1v,h2,h3);
    float f0=h0*mk, f1=h1v*mk, f2=h2*mk, f3=h3*mk;
    *(float4*)(hflat + (size_t)krow*256 + l*4) = make_float4(f0,f1,f2,f3);
    acc[kk][0]=f0*inv; acc[kk][1]=f1*inv; acc[kk][2]=f2*inv; acc[kk][3]=f3*inv;
  }
  if (l == 0) {
    #pragma unroll
    for (int kk = 0; kk < 8; ++kk) mask_out[b*32 + w*8 + kk] = mkarr[kk];
  }
  #pragma unroll
  for (int kk = 0; kk < 8; ++kk)
    *(float4*)(&hnlds[(w*8+kk)*260 + l*4]) =
        make_float4(acc[kk][0],acc[kk][1],acc[kk][2],acc[kk][3]);
  #pragma unroll
  for (int i = 0; i < 8; ++i) {
    int fid = t + i*256;
    *(float4*)(&unlds[fid*4]) = *(const float4*)(Un + fid*4);
  }
  __syncthreads();
  {
    const int k = t & 31, k2 = (t >> 5) * 4;
    float p0=0.f, p1=0.f, p2=0.f, p3=0.f;
    #pragma unroll 8
    for (int d4 = 0; d4 < 64; ++d4) {
      float4 hv = *(const float4*)(&hnlds[k*260 + d4*4]);
      float4 u0 = *(const float4*)(&unlds[(k2+0)*256 + d4*4]);
      float4 u1 = *(const float4*)(&unlds[(k2+1)*256 + d4*4]);
      float4 u2 = *(const float4*)(&unlds[(k2+2)*256 + d4*4]);
      float4 u3 = *(const float4*)(&unlds[(k2+3)*256 + d4*4]);
      p0 = fmaf(hv.x,u0.x,fmaf(hv.y,u0.y,fmaf(hv.z,u0.z,fmaf(hv.w,u0.w,p0))));
      p1 = fmaf(hv.x,u1.x,fmaf(hv.y,u1.y,fmaf(hv.z,u1.z,fmaf(hv.w,u1.w,p1))));
      p2 = fmaf(hv.x,u2.x,fmaf(hv.y,u2.y,fmaf(hv.z,u2.z,fmaf(hv.w,u2.w,p2))));
      p3 = fmaf(hv.x,u3.x,fmaf(hv.y,u3.y,fmaf(hv.z,u3.z,fmaf(hv.w,u3.w,p3))));
    }
    *(float4*)(p_out + (size_t)(b*32 + k)*32 + k2) = make_float4(p0,p1,p2,p3);
  }
}

// ============ K5a: partial sums of h_dense over b ============
__global__ __launch_bounds__(256) void k5a(const float* __restrict__ hdense,
                                           float* __restrict__ part)
{
  int k = blockIdx.x & 31, seg = blockIdx.x >> 5;
  int t = threadIdx.x;
  float s = 0.f;
  #pragma unroll 4
  for (int i = 0; i < 128; ++i) {
    int b = seg*128 + i;
    s += hdense[(size_t)(b*32 + k)*256 + t];
  }
  part[blockIdx.x*256 + t] = s;
}

// ============ K5b: sizes (reshape semantics!) + centroids + U_new ============
__global__ __launch_bounds__(256) void k5b(const float* __restrict__ part,
    const float* __restrict__ maskf, const float* __restrict__ U,
    float* __restrict__ Unew)
{
  __shared__ float r4[4];
  int k = blockIdx.x, t = threadIdx.x;
  float4 mv = *(const float4*)(maskf + k*1024 + t*4);
  float m4 = mv.x + mv.y + mv.z + mv.w;
  #pragma unroll
  for (int off = 1; off < 64; off <<= 1) m4 += __shfl_xor(m4, off);
  if ((t & 63) == 0) r4[t >> 6] = m4;
  __syncthreads();
  float sizes = r4[0] + r4[1] + r4[2] + r4[3];
  float csum = 0.f;
  #pragma unroll
  for (int g = 0; g < 8; ++g) csum += part[(g*32 + k)*256 + t];
  float cent = csum / (sizes + 1e-10f);
  Unew[k*256 + t] = 0.99f * U[k*256 + t] + 0.01f * cent;
}

// ============ K6: p_hat diag-embed ============
__global__ __launch_bounds__(256) void k6_phat(const float* __restrict__ c,
                                               float* __restrict__ phat)
{
  int idx = blockIdx.x*256 + threadIdx.x;
  int b = idx >> 10, rr = idx & 1023, k1 = rr >> 5, k2 = rr & 31;
  float v = 0.f;
  if (k1 == k2) { float cc = c[b*32 + k1]; v = cc / (cc + 1e-12f); }
  phat[idx] = v;
}

// ============ K7: z_dense = z copy, g passthrough (runs last: frees h1 region) ============
__global__ __launch_bounds__(256) void k7_copy(const float* __restrict__ z,
    const float* __restrict__ g, float* __restrict__ zd, float* __restrict__ gout)
{
  int idx = blockIdx.x*256 + threadIdx.x;
  if (idx < 8388608) {
    *(float4*)(zd + (size_t)idx*4) = *(const float4*)(z + (size_t)idx*4);
  } else {
    int j = idx - 8388608;
    *(float4*)(gout + (size_t)j*4) = *(const float4*)(g + (size_t)j*4);
  }
}

extern "C" void kernel_launch(void* const* d_in, const int* in_sizes, int n_in,
                              void* d_out, int out_size, void* d_ws, size_t ws_size,
                              hipStream_t stream)
{
  const float* z   = (const float*)d_in[0];
  const float* g   = (const float*)d_in[1];
  const float* W1  = (const float*)d_in[3];
  const float* b1  = (const float*)d_in[4];
  const float* gam = (const float*)d_in[5];
  const float* bet = (const float*)d_in[6];
  const float* W2  = (const float*)d_in[7];
  const float* b2  = (const float*)d_in[8];
  const float* U   = (const float*)d_in[9];
  float* out = (float*)d_out;
  float* ws  = (float*)d_ws;

  float* h1 = out + OFF_ZD;                         // stash h1 in z_dense region
  unsigned short* preh = (unsigned short*)(out + OFF_S);  // W1T scratch in s region
  unsigned short* prel = preh + 65536;              // (k3 overwrites s later)

  k0_prep<<<32, 256, 0, stream>>>(W1, preh, prel);
  k1_gemm1<<<1024, 512, 0, stream>>>(z, preh, prel, b1, h1, ws+WS_PSUM, ws+WS_PSQ);
  k2a<<<16, 256, 0, stream>>>(ws+WS_PSUM, ws+WS_PSQ, ws+WS_TMP);
  k2b<<<1, 256, 0, stream>>>(ws+WS_TMP, gam, bet, ws+WS_SCALE, ws+WS_SHIFT);
  k2c<<<32, 64, 0, stream>>>(U, ws+WS_UN);
  k3_gemm2<<<256, 256, 0, stream>>>(h1, W2, b2, ws+WS_SCALE, ws+WS_SHIFT,
                                    out+OFF_S, ws+WS_SF);
  k4_pool<<<1024, 256, 0, stream>>>(ws+WS_SF, z, ws+WS_UN, ws+WS_C,
                                    out+OFF_HDENSE, out+OFF_HFLAT,
                                    out+OFF_P, out+OFF_MASK);
  k5a<<<256, 256, 0, stream>>>(out+OFF_HDENSE, ws+WS_PART);
  k5b<<<32, 256, 0, stream>>>(ws+WS_PART, out+OFF_MASK, U, out+OFF_UNEW);
  k6_phat<<<4096, 256, 0, stream>>>(ws+WS_C, out+OFF_PHAT);
  k7_copy<<<33024, 256, 0, stream>>>(z, g, out+OFF_ZD, out+OFF_G);
}

// Round 3
// 327.228 us; speedup vs baseline: 1.4595x; 1.0898x over previous
//
#include <hip/hip_runtime.h>
#include <math.h>

#define NN 131072
#define BBG 1024
#define MMN 128
#define DDF 256
#define KKC 32

// ---- d_out offsets (floats), concatenated in reference return order ----
#define OFF_S      0
#define OFF_HFLAT  4194304
#define OFF_HDENSE 12582912
#define OFF_P      20971520
#define OFF_PHAT   22020096
#define OFF_ZD     23068672
#define OFF_G      56623104
#define OFF_MASK   56885248
#define OFF_UNEW   56918016

// ---- ws offsets (floats) ----
#define WS_PSUM  0          // [1024][256]
#define WS_PSQ   524288     // [1024][256]
#define WS_TMP   1048576    // [16][256]
#define WS_SCALE 1052672    // [256]
#define WS_SHIFT 1052928    // [256]
#define WS_UN    1053184    // [32][256]
#define WS_SF    1061376    // [N][32]
#define WS_C     5255680    // [B][32]
#define WS_PART  5288448    // [8*32][256]

typedef __attribute__((ext_vector_type(8))) short short8;
typedef __attribute__((ext_vector_type(4))) float f32x4;

__device__ __forceinline__ unsigned short f2bf(float x) {
  unsigned u = __float_as_uint(x);
  u += 0x7fffu + ((u >> 16) & 1u);
  return (unsigned short)(u >> 16);
}
__device__ __forceinline__ float bf2f(unsigned short h) {
  return __uint_as_float(((unsigned)h) << 16);
}

// ============ K0: W1 -> blocked bf16 hi/lo, layout [kstep][g][n][j] ============
// k = kstep*32 + g*8 + j ; element holds W1[k][n]. 8192 threads.
// This IS the per-lane B-fragment layout for mfma_f32_16x16x32_bf16:
// lane (lg,l16) at col nb reads 16B at [ks][lg][nb*8].
__global__ __launch_bounds__(256) void k0_prep(const float* __restrict__ W1,
    unsigned short* __restrict__ preh, unsigned short* __restrict__ prel)
{
  int tid = blockIdx.x * 256 + threadIdx.x;   // < 8192
  int n = tid & 255, kq = tid >> 8;           // kq in [0,32): k = kq*8 + j
  short8 hv, lv;
  #pragma unroll
  for (int j = 0; j < 8; ++j) {
    float v = W1[(kq * 8 + j) * DDF + n];
    unsigned short hb = f2bf(v);
    hv[j] = (short)hb;
    lv[j] = (short)f2bf(v - bf2f(hb));
  }
  int base = (kq >> 2) * 8192 + (kq & 3) * 2048 + n * 8;
  *(short8*)(preh + base) = hv;
  *(short8*)(prel + base) = lv;
}

// ============ K1: h1 = z@W1 + b1 via bf16x2-split MFMA + column stats ============
// 1024 blocks x 512 thr (8 waves, 2x4 grid, 64x64/wave). BK=32, 8 K-steps.
// Pipelined: A LDS double-buffered (1 raw barrier/step, lgkm-only drain),
// B fragments loaded DIRECTLY from global (L2-hot, no LDS, no conflicts).
__device__ __forceinline__ void cvt_storeA(float4 za, float4 zb,
    unsigned short* AhB, unsigned short* AlB, int arow, int ac)
{
  unsigned short h0 = f2bf(za.x), h1v = f2bf(za.y), h2 = f2bf(za.z), h3 = f2bf(za.w);
  unsigned short g0 = f2bf(zb.x), g1 = f2bf(zb.y), g2 = f2bf(zb.z), g3 = f2bf(zb.w);
  uint2 hA = make_uint2((unsigned)h0 | ((unsigned)h1v << 16),
                        (unsigned)h2 | ((unsigned)h3 << 16));
  uint2 hB = make_uint2((unsigned)g0 | ((unsigned)g1 << 16),
                        (unsigned)g2 | ((unsigned)g3 << 16));
  uint2 lA = make_uint2((unsigned)f2bf(za.x - bf2f(h0)) | ((unsigned)f2bf(za.y - bf2f(h1v)) << 16),
                        (unsigned)f2bf(za.z - bf2f(h2)) | ((unsigned)f2bf(za.w - bf2f(h3)) << 16));
  uint2 lB = make_uint2((unsigned)f2bf(zb.x - bf2f(g0)) | ((unsigned)f2bf(zb.y - bf2f(g1)) << 16),
                        (unsigned)f2bf(zb.z - bf2f(g2)) | ((unsigned)f2bf(zb.w - bf2f(g3)) << 16));
  *(uint2*)(AhB + arow * 40 + ac * 4)      = hA;
  *(uint2*)(AhB + arow * 40 + 16 + ac * 4) = hB;
  *(uint2*)(AlB + arow * 40 + ac * 4)      = lA;
  *(uint2*)(AlB + arow * 40 + 16 + ac * 4) = lB;
}

__global__ __launch_bounds__(512) void k1_gemm1(
    const float* __restrict__ z, const unsigned short* __restrict__ preh,
    const unsigned short* __restrict__ prel, const float* __restrict__ b1,
    float* __restrict__ h1, float* __restrict__ psum, float* __restrict__ psq)
{
  __shared__ __attribute__((aligned(16))) unsigned short Ah[2 * 128 * 40]; // 20.0 KB
  __shared__ __attribute__((aligned(16))) unsigned short Al[2 * 128 * 40]; // 20.0 KB

  const int t = threadIdx.x;
  const int l = t & 63;
  const int w = t >> 6;          // wave 0..7
  const int wr = w >> 2;         // 0..1  (row half)
  const int wc = w & 3;          // 0..3  (col quarter)
  const int lg = l >> 4;         // lane group 0..3 (k-chunk)
  const int l16 = l & 15;
  const int n0 = blockIdx.x * 128;

  f32x4 acc[4][4];
  #pragma unroll
  for (int i = 0; i < 4; ++i)
    #pragma unroll
    for (int j = 0; j < 4; ++j) acc[i][j] = (f32x4)0.0f;

  const int arow = t >> 2, ac = t & 3;
  const float* zrow = z + (size_t)(n0 + arow) * DDF;
  // B fragment base for this lane (nf advances by 128 shorts)
  const unsigned short* bhbase = preh + lg * 2048 + wc * 512 + l16 * 8;
  const unsigned short* blbase = prel + lg * 2048 + wc * 512 + l16 * 8;

  // prologue: stage A(0) into buf0
  {
    float4 za = *(const float4*)(zrow + ac * 4);
    float4 zb = *(const float4*)(zrow + 16 + ac * 4);
    cvt_storeA(za, zb, Ah, Al, arow, ac);
  }

  #pragma unroll
  for (int ks = 0; ks < 8; ++ks) {
    const int cur = (ks & 1) * 5120;
    const int nxt = 5120 - cur;
    // issue next-step z loads early (latency hides under MFMA phase)
    float4 za, zb;
    if (ks < 7) {
      za = *(const float4*)(zrow + (ks + 1) * 32 + ac * 4);
      zb = *(const float4*)(zrow + (ks + 1) * 32 + 16 + ac * 4);
    }
    // issue B fragment loads (L2-hot; latency hides under barrier + ds_reads)
    short8 bfh[4], bfl[4];
    #pragma unroll
    for (int nf = 0; nf < 4; ++nf) {
      bfh[nf] = *(const short8*)(bhbase + ks * 8192 + nf * 128);
      bfl[nf] = *(const short8*)(blbase + ks * 8192 + nf * 128);
    }
    // lgkm-only drain + raw barrier: global loads stay in flight (T4)
    asm volatile("s_waitcnt lgkmcnt(0)" ::: "memory");
    __builtin_amdgcn_s_barrier();
    __builtin_amdgcn_sched_barrier(0);
    // MFMA phase: A frags from LDS buf[cur]
    #pragma unroll
    for (int mf = 0; mf < 4; ++mf) {
      const int ar = wr * 64 + mf * 16 + l16;
      short8 afh = *(const short8*)(&Ah[cur + ar * 40 + lg * 8]);
      short8 afl = *(const short8*)(&Al[cur + ar * 40 + lg * 8]);
      #pragma unroll
      for (int nf = 0; nf < 4; ++nf) {
        acc[mf][nf] = __builtin_amdgcn_mfma_f32_16x16x32_bf16(afh, bfh[nf], acc[mf][nf], 0, 0, 0);
        acc[mf][nf] = __builtin_amdgcn_mfma_f32_16x16x32_bf16(afh, bfl[nf], acc[mf][nf], 0, 0, 0);
        acc[mf][nf] = __builtin_amdgcn_mfma_f32_16x16x32_bf16(afl, bfh[nf], acc[mf][nf], 0, 0, 0);
        acc[mf][nf] = __builtin_amdgcn_mfma_f32_16x16x32_bf16(afl, bfl[nf], acc[mf][nf], 0, 0, 0);
      }
    }
    // convert + stage A(ks+1) into the other buffer (write-late, T14)
    if (ks < 7) cvt_storeA(za, zb, Ah + nxt, Al + nxt, arow, ac);
  }

  // ---- epilogue: +b1, write h1 (C/D: col=l16, row=lg*4+j), column stats ----
  float s1[4] = {0, 0, 0, 0}, s2[4] = {0, 0, 0, 0};
  #pragma unroll
  for (int nf = 0; nf < 4; ++nf) {
    int c = wc * 64 + nf * 16 + l16;
    float bb = b1[c];
    #pragma unroll
    for (int mf = 0; mf < 4; ++mf) {
      int rbase = n0 + wr * 64 + mf * 16 + lg * 4;
      #pragma unroll
      for (int j = 0; j < 4; ++j) {
        float v = acc[mf][nf][j] + bb;
        s1[nf] += v; s2[nf] += v * v;
        h1[(size_t)(rbase + j) * DDF + c] = v;
      }
    }
  }
  #pragma unroll
  for (int nf = 0; nf < 4; ++nf) {
    s1[nf] += __shfl_xor(s1[nf], 16); s1[nf] += __shfl_xor(s1[nf], 32);
    s2[nf] += __shfl_xor(s2[nf], 16); s2[nf] += __shfl_xor(s2[nf], 32);
  }
  __syncthreads();                // done with MFMA LDS; reuse Ah/Al as f32 buffers
  float* red1 = (float*)Ah;       // [2][256]
  float* red2 = (float*)Al;       // [2][256]
  if (l < 16) {
    #pragma unroll
    for (int nf = 0; nf < 4; ++nf) {
      red1[wr * 256 + wc * 64 + nf * 16 + l] = s1[nf];
      red2[wr * 256 + wc * 64 + nf * 16 + l] = s2[nf];
    }
  }
  __syncthreads();
  if (t < 256) {
    psum[blockIdx.x * 256 + t] = red1[t] + red1[256 + t];
    psq [blockIdx.x * 256 + t] = red2[t] + red2[256 + t];
  }
}

// ============ K2a: reduce 1024 partial rows -> 16x256 ============
__global__ __launch_bounds__(256) void k2a(const float* __restrict__ psum,
                                           const float* __restrict__ psq,
                                           float* __restrict__ tmp)
{
  int g = blockIdx.x & 7;
  const float* src = (blockIdx.x < 8) ? psum : psq;
  float acc = 0.f;
  #pragma unroll 8
  for (int r = 0; r < 128; ++r) acc += src[(g * 128 + r) * 256 + threadIdx.x];
  tmp[blockIdx.x * 256 + threadIdx.x] = acc;
}

// ============ K2b: finalize BN scale/shift ============
__global__ __launch_bounds__(256) void k2b(const float* __restrict__ tmp,
    const float* __restrict__ gam, const float* __restrict__ bet,
    float* __restrict__ scale, float* __restrict__ shift)
{
  int d = threadIdx.x;
  float s1 = 0.f, s2 = 0.f;
  #pragma unroll
  for (int g = 0; g < 8; ++g) { s1 += tmp[g*256+d]; s2 += tmp[(8+g)*256+d]; }
  float mu  = s1 * (1.0f / (float)NN);
  float var = s2 * (1.0f / (float)NN) - mu*mu;
  float inv = 1.0f / sqrtf(var + 1e-5f);
  float sc = gam[d] * inv;
  scale[d] = sc;
  shift[d] = bet[d] - mu*sc;
}

// ============ K2c: Un = U / max(||U||,1e-12) ============
__global__ __launch_bounds__(64) void k2c(const float* __restrict__ U,
                                          float* __restrict__ Un)
{
  int k = blockIdx.x, l = threadIdx.x;
  float4 u = *(const float4*)(U + k*256 + l*4);
  float ss = u.x*u.x + u.y*u.y + u.z*u.z + u.w*u.w;
  #pragma unroll
  for (int off = 32; off >= 1; off >>= 1) ss += __shfl_xor(ss, off);
  float inv = 1.0f / fmaxf(sqrtf(ss), 1e-12f);
  *(float4*)(Un + k*256 + l*4) = make_float4(u.x*inv, u.y*inv, u.z*inv, u.w*inv);
}

// ============ K3: per-graph BN+lrelu+GEMM2+softmax+std-filter ============
__global__ __launch_bounds__(256) void k3_gemm2(
    const float* __restrict__ h1, const float* __restrict__ W2,
    const float* __restrict__ b2, const float* __restrict__ scale,
    const float* __restrict__ shift, float* __restrict__ s_out,
    float* __restrict__ sf_out)
{
  __shared__ float ylds[4][128*32];   // 64 KB, per-wave y tile (XOR-swizzled f4 slots)
  const int t = threadIdx.x;
  const int w = t >> 6, l = t & 63;
  const int b = blockIdx.x*4 + w;
  float* my = ylds[w];

  float acc0[32], acc1[32];
  #pragma unroll
  for (int k = 0; k < 32; ++k) { acc0[k] = 0.f; acc1[k] = 0.f; }

  const int slot  = l & 7;
  const int rbase = l >> 3;
  const int lx7   = l & 7;

  for (int ch = 0; ch < 8; ++ch) {
    const int dbase = ch*32 + slot*4;
    const float4 sc = *(const float4*)(scale + dbase);
    const float4 sh = *(const float4*)(shift + dbase);
    #pragma unroll
    for (int i = 0; i < 16; ++i) {
      int row = rbase + i*8;
      float4 v = *(const float4*)(h1 + (size_t)(b*MMN + row)*DDF + dbase);
      float y0 = fmaf(v.x, sc.x, sh.x); y0 = y0 > 0.f ? y0 : 0.01f*y0;
      float y1 = fmaf(v.y, sc.y, sh.y); y1 = y1 > 0.f ? y1 : 0.01f*y1;
      float y2 = fmaf(v.z, sc.z, sh.z); y2 = y2 > 0.f ? y2 : 0.01f*y2;
      float y3 = fmaf(v.w, sc.w, sh.w); y3 = y3 > 0.f ? y3 : 0.01f*y3;
      *(float4*)(&my[row*32 + (slot ^ (row & 7))*4]) = make_float4(y0,y1,y2,y3);
    }
    #pragma unroll
    for (int d4 = 0; d4 < 8; ++d4) {
      float4 ya = *(const float4*)(&my[ l     *32 + ((d4 ^ lx7))*4]);
      float4 yb = *(const float4*)(&my[(l+64)*32 + ((d4 ^ lx7))*4]);
      #pragma unroll
      for (int dd = 0; dd < 4; ++dd) {
        const float* w2r = W2 + (ch*32 + d4*4 + dd)*KKC;
        float a = (dd==0?ya.x: dd==1?ya.y: dd==2?ya.z: ya.w);
        float c = (dd==0?yb.x: dd==1?yb.y: dd==2?yb.z: yb.w);
        #pragma unroll
        for (int k = 0; k < 32; ++k) {
          float wv = w2r[k];
          acc0[k] = fmaf(a, wv, acc0[k]);
          acc1[k] = fmaf(c, wv, acc1[k]);
        }
      }
    }
  }
  #pragma unroll
  for (int k = 0; k < 32; ++k) {
    float bb = b2[k];
    acc0[k] = (acc0[k] + bb) * 10.0f;
    acc1[k] = (acc1[k] + bb) * 10.0f;
  }
  float thr0, thr1;
  {
    float* a = acc0; float* thrp = &thr0;
    #pragma unroll
    for (int r = 0; r < 2; ++r) {
      float m = a[0];
      #pragma unroll
      for (int k = 1; k < 32; ++k) m = fmaxf(m, a[k]);
      float sum = 0.f;
      #pragma unroll
      for (int k = 0; k < 32; ++k) { float e = expf(a[k]-m); a[k] = e; sum += e; }
      float inv = 1.0f/sum;
      float ssum = 0.f;
      #pragma unroll
      for (int k = 0; k < 32; ++k) { a[k] *= inv; ssum += a[k]; }
      float mean = ssum * (1.0f/32.0f);
      float var = 0.f;
      #pragma unroll
      for (int k = 0; k < 32; ++k) { float d = a[k]-mean; var += d*d; }
      *thrp = sqrtf(var * (1.0f/31.0f)) + 0.03125f;
      a = acc1; thrp = &thr1;
    }
  }
  #pragma unroll
  for (int q = 0; q < 8; ++q) {
    *(float4*)(&my[ l     *32 + (q ^ lx7)*4]) =
        make_float4(acc0[q*4],acc0[q*4+1],acc0[q*4+2],acc0[q*4+3]);
    *(float4*)(&my[(l+64)*32 + (q ^ lx7)*4]) =
        make_float4(acc1[q*4],acc1[q*4+1],acc1[q*4+2],acc1[q*4+3]);
  }
  #pragma unroll
  for (int i = 0; i < 16; ++i) {
    int fid = l + i*64;
    int row = fid >> 3, q = fid & 7;
    *(float4*)(s_out + (size_t)b*4096 + fid*4) =
        *(const float4*)(&my[row*32 + (q ^ (row & 7))*4]);
  }
  #pragma unroll
  for (int k = 0; k < 32; ++k) {
    acc0[k] = acc0[k] > thr0 ? acc0[k] : 0.f;
    acc1[k] = acc1[k] > thr1 ? acc1[k] : 0.f;
  }
  #pragma unroll
  for (int q = 0; q < 8; ++q) {
    *(float4*)(&my[ l     *32 + (q ^ lx7)*4]) =
        make_float4(acc0[q*4],acc0[q*4+1],acc0[q*4+2],acc0[q*4+3]);
    *(float4*)(&my[(l+64)*32 + (q ^ lx7)*4]) =
        make_float4(acc1[q*4],acc1[q*4+1],acc1[q*4+2],acc1[q*4+3]);
  }
  #pragma unroll
  for (int i = 0; i < 16; ++i) {
    int fid = l + i*64;
    int row = fid >> 3, q = fid & 7;
    *(float4*)(sf_out + (size_t)b*4096 + fid*4) =
        *(const float4*)(&my[row*32 + (q ^ (row & 7))*4]);
  }
}

// ============ K4: per-graph pooling + h_dense/h_flat/mask + hn + p + zd ============
__global__ __launch_bounds__(256) void k4_pool(
    const float* __restrict__ sf, const float* __restrict__ z,
    const float* __restrict__ Un, float* __restrict__ c_out,
    float* __restrict__ hdense, float* __restrict__ hflat,
    float* __restrict__ p_out, float* __restrict__ mask_out,
    float* __restrict__ zd)
{
  __shared__ __align__(16) char smem[66048];
  __shared__ float redp[8*32];
  __shared__ float cred[32];
  float* sflds = (float*)smem;
  float* zlds  = (float*)(smem + 16384);
  float* hnlds = (float*)smem;
  float* unlds = (float*)(smem + 33280);

  const int t = threadIdx.x;
  const int w = t >> 6, l = t & 63;
  const int b = blockIdx.x;

  #pragma unroll
  for (int i = 0; i < 4; ++i) {
    int fid = t + i*256;
    *(float4*)(&sflds[fid*4]) = *(const float4*)(sf + (size_t)b*4096 + fid*4);
  }
  __syncthreads();
  {
    int k = t & 31, mg = t >> 5;
    float p = 0.f;
    #pragma unroll
    for (int m = 0; m < 16; ++m) p += sflds[(mg*16+m)*32 + k];
    redp[mg*32 + k] = p;
  }
  __syncthreads();
  if (t < 32) {
    float c = 0.f;
    #pragma unroll
    for (int g = 0; g < 8; ++g) c += redp[g*32 + t];
    cred[t] = c;
    c_out[b*32 + t] = c;
  }
  __syncthreads();

  float acc[8][4];
  #pragma unroll
  for (int kk = 0; kk < 8; ++kk)
    #pragma unroll
    for (int j = 0; j < 4; ++j) acc[kk][j] = 0.f;

  for (int ch = 0; ch < 4; ++ch) {
    #pragma unroll
    for (int i = 0; i < 8; ++i) {
      int fid = t + i*256;
      float4 v = *(const float4*)(z + (size_t)(b*128 + ch*32)*256 + fid*4);
      *(float4*)(&zlds[fid*4]) = v;
      *(float4*)(zd + (size_t)(b*128 + ch*32)*256 + fid*4) = v;  // z_dense output
    }
    __syncthreads();
    #pragma unroll
    for (int mm = 0; mm < 32; ++mm) {
      float4 zv = *(const float4*)(&zlds[mm*256 + l*4]);
      float4 sa = *(const float4*)(&sflds[(ch*32+mm)*32 + w*8]);
      float4 sb = *(const float4*)(&sflds[(ch*32+mm)*32 + w*8 + 4]);
      float sv[8] = {sa.x,sa.y,sa.z,sa.w,sb.x,sb.y,sb.z,sb.w};
      #pragma unroll
      for (int kk = 0; kk < 8; ++kk) {
        acc[kk][0] = fmaf(sv[kk], zv.x, acc[kk][0]);
        acc[kk][1] = fmaf(sv[kk], zv.y, acc[kk][1]);
        acc[kk][2] = fmaf(sv[kk], zv.z, acc[kk][2]);
        acc[kk][3] = fmaf(sv[kk], zv.w, acc[kk][3]);
      }
    }
    __syncthreads();
  }
  float asum[8], qsum[8], mkarr[8];
  #pragma unroll
  for (int kk = 0; kk < 8; ++kk) {
    float wnv = 1.0f / fmaxf(cred[w*8+kk], 1e-12f);
    acc[kk][0]*=wnv; acc[kk][1]*=wnv; acc[kk][2]*=wnv; acc[kk][3]*=wnv;
    asum[kk] = fabsf(acc[kk][0])+fabsf(acc[kk][1])+fabsf(acc[kk][2])+fabsf(acc[kk][3]);
    qsum[kk] = acc[kk][0]*acc[kk][0]+acc[kk][1]*acc[kk][1]
             + acc[kk][2]*acc[kk][2]+acc[kk][3]*acc[kk][3];
  }
  #pragma unroll
  for (int kk = 0; kk < 8; ++kk) {
    float a = asum[kk], q = qsum[kk];
    #pragma unroll
    for (int off = 1; off < 64; off <<= 1) {
      a += __shfl_xor(a, off); q += __shfl_xor(q, off);
    }
    asum[kk] = a; qsum[kk] = q;
  }
  #pragma unroll
  for (int kk = 0; kk < 8; ++kk) {
    int krow = b*32 + w*8 + kk;
    float mk = asum[kk] > 0.f ? 1.0f : 0.0f;
    mkarr[kk] = mk;
    float inv = 1.0f / fmaxf(sqrtf(qsum[kk]) * mk, 1e-12f);
    float h0=acc[kk][0], h1v=acc[kk][1], h2=acc[kk][2], h3=acc[kk][3];
    *(float4*)(hdense + (size_t)krow*256 + l*4) = make_float4(h0,h1v,h2,h3);
    float f0=h0*mk, f1=h1v*mk, f2=h2*mk, f3=h3*mk;
    *(float4*)(hflat + (size_t)krow*256 + l*4) = make_float4(f0,f1,f2,f3);
    acc[kk][0]=f0*inv; acc[kk][1]=f1*inv; acc[kk][2]=f2*inv; acc[kk][3]=f3*inv;
  }
  if (l == 0) {
    #pragma unroll
    for (int kk = 0; kk < 8; ++kk) mask_out[b*32 + w*8 + kk] = mkarr[kk];
  }
  #pragma unroll
  for (int kk = 0; kk < 8; ++kk)
    *(float4*)(&hnlds[(w*8+kk)*260 + l*4]) =
        make_float4(acc[kk][0],acc[kk][1],acc[kk][2],acc[kk][3]);
  #pragma unroll
  for (int i = 0; i < 8; ++i) {
    int fid = t + i*256;
    *(float4*)(&unlds[fid*4]) = *(const float4*)(Un + fid*4);
  }
  __syncthreads();
  {
    const int k = t & 31, k2 = (t >> 5) * 4;
    float p0=0.f, p1=0.f, p2=0.f, p3=0.f;
    #pragma unroll 8
    for (int d4 = 0; d4 < 64; ++d4) {
      float4 hv = *(const float4*)(&hnlds[k*260 + d4*4]);
      float4 u0 = *(const float4*)(&unlds[(k2+0)*256 + d4*4]);
      float4 u1 = *(const float4*)(&unlds[(k2+1)*256 + d4*4]);
      float4 u2 = *(const float4*)(&unlds[(k2+2)*256 + d4*4]);
      float4 u3 = *(const float4*)(&unlds[(k2+3)*256 + d4*4]);
      p0 = fmaf(hv.x,u0.x,fmaf(hv.y,u0.y,fmaf(hv.z,u0.z,fmaf(hv.w,u0.w,p0))));
      p1 = fmaf(hv.x,u1.x,fmaf(hv.y,u1.y,fmaf(hv.z,u1.z,fmaf(hv.w,u1.w,p1))));
      p2 = fmaf(hv.x,u2.x,fmaf(hv.y,u2.y,fmaf(hv.z,u2.z,fmaf(hv.w,u2.w,p2))));
      p3 = fmaf(hv.x,u3.x,fmaf(hv.y,u3.y,fmaf(hv.z,u3.z,fmaf(hv.w,u3.w,p3))));
    }
    *(float4*)(p_out + (size_t)(b*32 + k)*32 + k2) = make_float4(p0,p1,p2,p3);
  }
}

// ============ K5a: partial sums of h_dense over b ============
__global__ __launch_bounds__(256) void k5a(const float* __restrict__ hdense,
                                           float* __restrict__ part)
{
  int k = blockIdx.x & 31, seg = blockIdx.x >> 5;
  int t = threadIdx.x;
  float s = 0.f;
  #pragma unroll 4
  for (int i = 0; i < 128; ++i) {
    int b = seg*128 + i;
    s += hdense[(size_t)(b*32 + k)*256 + t];
  }
  part[blockIdx.x*256 + t] = s;
}

// ============ K5b: sizes (reshape semantics!) + centroids + U_new ============
__global__ __launch_bounds__(256) void k5b(const float* __restrict__ part,
    const float* __restrict__ maskf, const float* __restrict__ U,
    float* __restrict__ Unew)
{
  __shared__ float r4[4];
  int k = blockIdx.x, t = threadIdx.x;
  float4 mv = *(const float4*)(maskf + k*1024 + t*4);
  float m4 = mv.x + mv.y + mv.z + mv.w;
  #pragma unroll
  for (int off = 1; off < 64; off <<= 1) m4 += __shfl_xor(m4, off);
  if ((t & 63) == 0) r4[t >> 6] = m4;
  __syncthreads();
  float sizes = r4[0] + r4[1] + r4[2] + r4[3];
  float csum = 0.f;
  #pragma unroll
  for (int g = 0; g < 8; ++g) csum += part[(g*32 + k)*256 + t];
  float cent = csum / (sizes + 1e-10f);
  Unew[k*256 + t] = 0.99f * U[k*256 + t] + 0.01f * cent;
}

// ============ K6: p_hat diag-embed ============
__global__ __launch_bounds__(256) void k6_phat(const float* __restrict__ c,
                                               float* __restrict__ phat)
{
  int idx = blockIdx.x*256 + threadIdx.x;
  int b = idx >> 10, rr = idx & 1023, k1 = rr >> 5, k2 = rr & 31;
  float v = 0.f;
  if (k1 == k2) { float cc = c[b*32 + k1]; v = cc / (cc + 1e-12f); }
  phat[idx] = v;
}

// ============ K7: g passthrough only (z_dense now written by K4) ============
__global__ __launch_bounds__(256) void k7_copy(const float* __restrict__ g,
                                               float* __restrict__ gout)
{
  int idx = blockIdx.x*256 + threadIdx.x;   // < 65536 float4s
  *(float4*)(gout + (size_t)idx*4) = *(const float4*)(g + (size_t)idx*4);
}

extern "C" void kernel_launch(void* const* d_in, const int* in_sizes, int n_in,
                              void* d_out, int out_size, void* d_ws, size_t ws_size,
                              hipStream_t stream)
{
  const float* z   = (const float*)d_in[0];
  const float* g   = (const float*)d_in[1];
  const float* W1  = (const float*)d_in[3];
  const float* b1  = (const float*)d_in[4];
  const float* gam = (const float*)d_in[5];
  const float* bet = (const float*)d_in[6];
  const float* W2  = (const float*)d_in[7];
  const float* b2  = (const float*)d_in[8];
  const float* U   = (const float*)d_in[9];
  float* out = (float*)d_out;
  float* ws  = (float*)d_ws;

  float* h1 = out + OFF_ZD;                         // stash h1 in z_dense region
  unsigned short* preh = (unsigned short*)(out + OFF_S);  // W1T scratch in s region
  unsigned short* prel = preh + 65536;              // (k3 overwrites s later)

  k0_prep<<<32, 256, 0, stream>>>(W1, preh, prel);
  k1_gemm1<<<1024, 512, 0, stream>>>(z, preh, prel, b1, h1, ws+WS_PSUM, ws+WS_PSQ);
  k2a<<<16, 256, 0, stream>>>(ws+WS_PSUM, ws+WS_PSQ, ws+WS_TMP);
  k2b<<<1, 256, 0, stream>>>(ws+WS_TMP, gam, bet, ws+WS_SCALE, ws+WS_SHIFT);
  k2c<<<32, 64, 0, stream>>>(U, ws+WS_UN);
  k3_gemm2<<<256, 256, 0, stream>>>(h1, W2, b2, ws+WS_SCALE, ws+WS_SHIFT,
                                    out+OFF_S, ws+WS_SF);
  k4_pool<<<1024, 256, 0, stream>>>(ws+WS_SF, z, ws+WS_UN, ws+WS_C,
                                    out+OFF_HDENSE, out+OFF_HFLAT,
                                    out+OFF_P, out+OFF_MASK, out+OFF_ZD);
  k5a<<<256, 256, 0, stream>>>(out+OFF_HDENSE, ws+WS_PART);
  k5b<<<32, 256, 0, stream>>>(ws+WS_PART, out+OFF_MASK, U, out+OFF_UNEW);
  k6_phat<<<4096, 256, 0, stream>>>(ws+WS_C, out+OFF_PHAT);
  k7_copy<<<256, 256, 0, stream>>>(g, out+OFF_G);
}